// Round 4
// baseline (1907.505 us; speedup 1.0000x reference)
//
#include <hip/hip_runtime.h>

// SiameseBrainNet: 3-layer GCN encoder (shared weights) x2 + mean-pool + pairwise distance.
// D = H = 512 hard-coded. GEMMs: split-bf16 (hi/lo) 3-MFMA fp32 emulation on
// v_mfma_f32_16x16x32_bf16. Staging via global_load_lds (width 16), linear LDS tiles.

typedef short bf16x8 __attribute__((ext_vector_type(8)));
typedef float f32x4 __attribute__((ext_vector_type(4)));

__device__ __forceinline__ unsigned short f2bf(float f) {
    union { float f; unsigned u; } v; v.f = f;
    unsigned r = (v.u + 0x7fffu + ((v.u >> 16) & 1u)) >> 16;  // RNE
    return (unsigned short)r;
}
__device__ __forceinline__ float bf2f(unsigned short h) {
    union { unsigned u; float f; } v; v.u = ((unsigned)h) << 16;
    return v.f;
}

__device__ __forceinline__ void gload16(const unsigned short* g, unsigned short* lds) {
    __builtin_amdgcn_global_load_lds(
        (const __attribute__((address_space(1))) unsigned int*)g,
        (__attribute__((address_space(3))) unsigned int*)lds, 16, 0, 0);
}

// ---------------- CSR build ----------------

__global__ __launch_bounds__(256) void deg_kernel(const int* __restrict__ dst,
                                                  int* __restrict__ deg, int e) {
    int i = blockIdx.x * 256 + threadIdx.x;
    if (i < e) atomicAdd(&deg[dst[i]], 1);
}

__global__ __launch_bounds__(256) void dinv_kernel(const int* __restrict__ deg,
                                                   float* __restrict__ dinv, int n) {
    int i = blockIdx.x * 256 + threadIdx.x;
    if (i < n) dinv[i] = rsqrtf((float)deg[i] + 1.0f);  // self-loop: deg+1
}

__global__ __launch_bounds__(1024) void scan_kernel(const int* __restrict__ deg,
                                                    int* __restrict__ row_ptr,
                                                    int* __restrict__ cursor, int n) {
    __shared__ int sums[1024];
    int t = threadIdx.x;
    int chunk = (n + 1023) >> 10;
    int beg = t * chunk;
    int end = beg + chunk;
    if (beg > n) beg = n;
    if (end > n) end = n;
    int s = 0;
    for (int i = beg; i < end; ++i) s += deg[i];
    sums[t] = s;
    __syncthreads();
    for (int off = 1; off < 1024; off <<= 1) {
        int v = (t >= off) ? sums[t - off] : 0;
        __syncthreads();
        sums[t] += v;
        __syncthreads();
    }
    int run = sums[t] - s;
    for (int i = beg; i < end; ++i) {
        row_ptr[i] = run;
        cursor[i] = run;
        run += deg[i];
    }
    if (t == 1023) row_ptr[n] = sums[1023];
}

__global__ __launch_bounds__(256) void fill_kernel(const int* __restrict__ src,
                                                   const int* __restrict__ dst,
                                                   const float* __restrict__ dinv,
                                                   int* __restrict__ cursor,
                                                   int* __restrict__ csr_src,
                                                   float* __restrict__ csr_norm, int e) {
    int i = blockIdx.x * 256 + threadIdx.x;
    if (i >= e) return;
    int s = src[i], d = dst[i];
    int p = atomicAdd(&cursor[d], 1);
    csr_src[p] = s;
    csr_norm[p] = dinv[s] * dinv[d];
}

// ---------------- graph ranges from sorted batch ----------------

__global__ __launch_bounds__(256) void ranges_kernel(const int* __restrict__ batch,
                                                     int* __restrict__ start, int n, int g) {
    int i = blockIdx.x * 256 + threadIdx.x;
    if (i >= n) return;
    int b = batch[i];
    if (i == 0) {
        for (int k = 0; k <= b; ++k) start[k] = 0;
    } else {
        int pb = batch[i - 1];
        for (int k = pb + 1; k <= b; ++k) start[k] = i;
    }
    if (i == n - 1) {
        for (int k = b + 1; k <= g; ++k) start[k] = n;
    }
}

// ---------------- W pre-transpose + bf16 hi/lo split ----------------
// W [512(k)][512(n)] fp32 -> Wt_hi/Wt_lo [512(n)][512(k)] bf16.

__global__ __launch_bounds__(256) void wsplit_kernel(const float* __restrict__ W,
                                                     unsigned short* __restrict__ Wt_hi,
                                                     unsigned short* __restrict__ Wt_lo) {
    __shared__ float tile[32][33];
    int b = blockIdx.x;
    int k0 = (b & 15) * 32, n0 = (b >> 4) * 32;
    int t = threadIdx.x;
    int tc = t & 31, tr = t >> 5;  // 8 rows/iter
#pragma unroll
    for (int it = 0; it < 4; ++it)
        tile[tr + it * 8][tc] = W[(size_t)(k0 + tr + it * 8) * 512 + n0 + tc];
    __syncthreads();
#pragma unroll
    for (int it = 0; it < 4; ++it) {
        int n = tr + it * 8;
        float v = tile[tc][n];
        unsigned short hi = f2bf(v);
        unsigned short lo = f2bf(v - bf2f(hi));
        Wt_hi[(size_t)(n0 + n) * 512 + k0 + tc] = hi;
        Wt_lo[(size_t)(n0 + n) * 512 + k0 + tc] = lo;
    }
}

// ---------------- A bf16 hi/lo split (elementwise; only for layer-1 input) ----------------

__global__ __launch_bounds__(256) void asplit_kernel(const float* __restrict__ A,
                                                     unsigned short* __restrict__ A_hi,
                                                     unsigned short* __restrict__ A_lo,
                                                     int n4) {
    int i = blockIdx.x * 256 + threadIdx.x;
    if (i >= n4) return;
    float4 v = ((const float4*)A)[i];
    ushort4 h, l;
    h.x = f2bf(v.x); l.x = f2bf(v.x - bf2f(h.x));
    h.y = f2bf(v.y); l.y = f2bf(v.y - bf2f(h.y));
    h.z = f2bf(v.z); l.z = f2bf(v.z - bf2f(h.z));
    h.w = f2bf(v.w); l.w = f2bf(v.w - bf2f(h.w));
    ((ushort4*)A_hi)[i] = h;
    ((ushort4*)A_lo)[i] = l;
}

// ---------------- split-bf16 MFMA GEMM: C[M x 512] = A[M x 512] @ W[512 x 512] ----------------
// BM=128 BN=128 BK=32, 256 threads (4 waves, 2x2), per-wave 64x64 via 4x4 frags of 16x16x32.
// A pre-split [m][k] bf16; B pre-transposed+split [n][k] bf16.
// Staging: global_load_lds dwordx4, linear LDS (wave-uniform dest + lane*16 rule).

__global__ __launch_bounds__(256) void gemm_mfma_kernel(const unsigned short* __restrict__ A_hi,
                                                        const unsigned short* __restrict__ A_lo,
                                                        const unsigned short* __restrict__ Bt_hi,
                                                        const unsigned short* __restrict__ Bt_lo,
                                                        float* __restrict__ C, int M) {
    __shared__ unsigned short As_hi[128][32], As_lo[128][32];  // 8 KB each
    __shared__ unsigned short Bs_hi[128][32], Bs_lo[128][32];  // total 32 KB
    int nb = blockIdx.x & 3;  // 512/128 = 4 col-blocks
    int mb = blockIdx.x >> 2;
    int row0 = mb * 128, col0 = nb * 128;
    int t = threadIdx.x;
    int lane = t & 63, w = t >> 6;
    int wm = w >> 1, wn = w & 1;
    int r = lane & 15, g = lane >> 4;

    f32x4 acc[4][4] = {};

    int r4 = t >> 2;          // 0..63: row within half-tile
    int kq = (t & 3) * 8;     // k-quarter (elements)

    for (int k0 = 0; k0 < 512; k0 += 32) {
        // stage: 8x global_load_lds_dwordx4 (wave-uniform LDS base; HW adds lane*16B)
#pragma unroll
        for (int i = 0; i < 2; ++i) {
            int ldsrow = i * 64 + w * 16;
            gload16(A_hi + (size_t)(row0 + i * 64 + r4) * 512 + k0 + kq, &As_hi[ldsrow][0]);
            gload16(A_lo + (size_t)(row0 + i * 64 + r4) * 512 + k0 + kq, &As_lo[ldsrow][0]);
            gload16(Bt_hi + (size_t)(col0 + i * 64 + r4) * 512 + k0 + kq, &Bs_hi[ldsrow][0]);
            gload16(Bt_lo + (size_t)(col0 + i * 64 + r4) * 512 + k0 + kq, &Bs_lo[ldsrow][0]);
        }
        __syncthreads();  // drains vmcnt (global_load_lds) + lgkm

        bf16x8 ah[4], al[4], bh[4], bl[4];
#pragma unroll
        for (int m = 0; m < 4; ++m) {
            int rr = wm * 64 + m * 16 + r;
            ah[m] = *(const bf16x8*)&As_hi[rr][g * 8];
            al[m] = *(const bf16x8*)&As_lo[rr][g * 8];
        }
#pragma unroll
        for (int n = 0; n < 4; ++n) {
            int cc = wn * 64 + n * 16 + r;
            bh[n] = *(const bf16x8*)&Bs_hi[cc][g * 8];
            bl[n] = *(const bf16x8*)&Bs_lo[cc][g * 8];
        }
#pragma unroll
        for (int m = 0; m < 4; ++m)
#pragma unroll
            for (int n = 0; n < 4; ++n) {
                acc[m][n] = __builtin_amdgcn_mfma_f32_16x16x32_bf16(al[m], bh[n], acc[m][n], 0, 0, 0);
                acc[m][n] = __builtin_amdgcn_mfma_f32_16x16x32_bf16(ah[m], bl[n], acc[m][n], 0, 0, 0);
                acc[m][n] = __builtin_amdgcn_mfma_f32_16x16x32_bf16(ah[m], bh[n], acc[m][n], 0, 0, 0);
            }
        __syncthreads();
    }

#pragma unroll
    for (int m = 0; m < 4; ++m)
#pragma unroll
        for (int j = 0; j < 4; ++j) {
            int rr = row0 + wm * 64 + m * 16 + g * 4 + j;
            if (rr < M) {
#pragma unroll
                for (int n = 0; n < 4; ++n)
                    C[(size_t)rr * 512 + col0 + wn * 64 + n * 16 + r] = acc[m][n][j];
            }
        }
}

// ---------------- aggregation: agg[d] = sum_{e: dst=d} h[src]*norm + h[d]*dinv[d]^2 + b ----------------
// one block per dst node; fused bias + optional relu; optionally emits bf16 hi/lo for next GEMM.

template <bool RELU, bool SPLIT>
__global__ __launch_bounds__(256) void aggregate_kernel(const float* __restrict__ H,
                                                        const int* __restrict__ row_ptr,
                                                        const int* __restrict__ csr_src,
                                                        const float* __restrict__ csr_norm,
                                                        const float* __restrict__ dinv,
                                                        const float* __restrict__ bias,
                                                        float* __restrict__ X,
                                                        unsigned short* __restrict__ Xhi,
                                                        unsigned short* __restrict__ Xlo) {
    int d = blockIdx.x;
    int t = threadIdx.x;
    int beg = row_ptr[d], end = row_ptr[d + 1];
    float ax = 0.f, ay = 0.f;
    for (int j = beg; j < end; ++j) {
        int s = csr_src[j];
        float w = csr_norm[j];
        float2 hv = *(const float2*)(H + (size_t)s * 512 + t * 2);
        ax += w * hv.x;
        ay += w * hv.y;
    }
    float di = dinv[d];
    float self = di * di;
    float2 hd = *(const float2*)(H + (size_t)d * 512 + t * 2);
    float2 bb = *(const float2*)(bias + t * 2);
    float ox = ax + self * hd.x + bb.x;
    float oy = ay + self * hd.y + bb.y;
    if (RELU) {
        ox = fmaxf(ox, 0.f);
        oy = fmaxf(oy, 0.f);
    }
    if (SPLIT) {
        unsigned short hx = f2bf(ox), hy = f2bf(oy);
        unsigned short lx = f2bf(ox - bf2f(hx)), ly = f2bf(oy - bf2f(hy));
        *(ushort2*)(Xhi + (size_t)d * 512 + t * 2) = make_ushort2(hx, hy);
        *(ushort2*)(Xlo + (size_t)d * 512 + t * 2) = make_ushort2(lx, ly);
    } else {
        *(float2*)(X + (size_t)d * 512 + t * 2) = make_float2(ox, oy);
    }
}

// ---------------- mean pool over sorted-batch ranges ----------------

__global__ __launch_bounds__(256) void pool_kernel(const float* __restrict__ X,
                                                   const int* __restrict__ start,
                                                   float* __restrict__ pool) {
    int g = blockIdx.x;
    int t = threadIdx.x;
    int s = start[g], e = start[g + 1];
    float ax = 0.f, ay = 0.f;
    for (int n = s; n < e; ++n) {
        float2 v = *(const float2*)(X + (size_t)n * 512 + t * 2);
        ax += v.x;
        ay += v.y;
    }
    float cnt = (float)(e - s);
    cnt = fmaxf(cnt, 1.0f);
    *(float2*)(pool + (size_t)g * 512 + t * 2) = make_float2(ax / cnt, ay / cnt);
}

// ---------------- pairwise distance ----------------

__global__ __launch_bounds__(64) void pdist_kernel(const float* __restrict__ pa,
                                                   const float* __restrict__ pb,
                                                   float* __restrict__ out) {
    int g = blockIdx.x;
    int t = threadIdx.x;
    float s = 0.f;
    for (int i = t; i < 512; i += 64) {
        float d = pa[(size_t)g * 512 + i] - pb[(size_t)g * 512 + i] + 1e-6f;
        s += d * d;
    }
#pragma unroll
    for (int off = 32; off; off >>= 1) s += __shfl_down(s, off);
    if (t == 0) out[g] = sqrtf(s);
}

// ---------------- launch ----------------

extern "C" void kernel_launch(void* const* d_in, const int* in_sizes, int n_in,
                              void* d_out, int out_size, void* d_ws, size_t ws_size,
                              hipStream_t stream) {
    const float* x_a = (const float*)d_in[0];
    const int* ei_a = (const int*)d_in[1];
    const int* batch_a = (const int*)d_in[2];
    const float* x_b = (const float*)d_in[3];
    const int* ei_b = (const int*)d_in[4];
    const int* batch_b = (const int*)d_in[5];
    const float* W1 = (const float*)d_in[6];
    const float* b1 = (const float*)d_in[7];
    const float* W2 = (const float*)d_in[8];
    const float* b2 = (const float*)d_in[9];
    const float* W3 = (const float*)d_in[10];
    const float* b3 = (const float*)d_in[11];
    float* out = (float*)d_out;

    const int N = in_sizes[0] / 512;
    const int E = in_sizes[1] / 2;
    const int G = out_size;

    char* ws = (char*)d_ws;
    size_t off = 0;
    auto alloc = [&](size_t bytes) -> void* {
        void* p = ws + off;
        off = (off + bytes + 255) & ~(size_t)255;
        return p;
    };
    float* bufH = (float*)alloc((size_t)N * 512 * 4);
    float* bufX = (float*)alloc((size_t)N * 512 * 4);
    unsigned short* a_hi = (unsigned short*)alloc((size_t)N * 512 * 2);
    unsigned short* a_lo = (unsigned short*)alloc((size_t)N * 512 * 2);
    int* deg = (int*)alloc((size_t)N * 4);
    float* dinv = (float*)alloc((size_t)N * 4);
    int* row_ptr = (int*)alloc((size_t)(N + 1) * 4);
    int* cursor = (int*)alloc((size_t)N * 4);
    int* csr_src = (int*)alloc((size_t)E * 4);
    float* csr_norm = (float*)alloc((size_t)E * 4);
    int* start = (int*)alloc((size_t)(G + 1) * 4);
    float* pool_a = (float*)alloc((size_t)G * 512 * 4);
    float* pool_b = (float*)alloc((size_t)G * 512 * 4);
    unsigned short* wt_hi[3];
    unsigned short* wt_lo[3];
    for (int i = 0; i < 3; ++i) {
        wt_hi[i] = (unsigned short*)alloc((size_t)512 * 512 * 2);
        wt_lo[i] = (unsigned short*)alloc((size_t)512 * 512 * 2);
    }

    const int ebl = (E + 255) / 256;
    const int nbl = (N + 255) / 256;
    const int gemm_grid = 4 * ((N + 127) / 128);
    const int n4 = N * 512 / 4;
    const int abl = (n4 + 255) / 256;

    // pre-split weights (once per launch; graph-capture safe, same work every call)
    wsplit_kernel<<<256, 256, 0, stream>>>(W1, wt_hi[0], wt_lo[0]);
    wsplit_kernel<<<256, 256, 0, stream>>>(W2, wt_hi[1], wt_lo[1]);
    wsplit_kernel<<<256, 256, 0, stream>>>(W3, wt_hi[2], wt_lo[2]);

    auto encode = [&](const float* x_in, const int* ei, const int* batch, float* pool) {
        const int* src = ei;
        const int* dst = ei + E;
        hipMemsetAsync(deg, 0, (size_t)N * 4, stream);
        deg_kernel<<<ebl, 256, 0, stream>>>(dst, deg, E);
        dinv_kernel<<<nbl, 256, 0, stream>>>(deg, dinv, N);
        scan_kernel<<<1, 1024, 0, stream>>>(deg, row_ptr, cursor, N);
        fill_kernel<<<ebl, 256, 0, stream>>>(src, dst, dinv, cursor, csr_src, csr_norm, E);
        ranges_kernel<<<nbl, 256, 0, stream>>>(batch, start, N, G);

        asplit_kernel<<<abl, 256, 0, stream>>>(x_in, a_hi, a_lo, n4);
        gemm_mfma_kernel<<<gemm_grid, 256, 0, stream>>>(a_hi, a_lo, wt_hi[0], wt_lo[0], bufH, N);
        aggregate_kernel<true, true><<<N, 256, 0, stream>>>(bufH, row_ptr, csr_src, csr_norm,
                                                            dinv, b1, bufX, a_hi, a_lo);
        gemm_mfma_kernel<<<gemm_grid, 256, 0, stream>>>(a_hi, a_lo, wt_hi[1], wt_lo[1], bufH, N);
        aggregate_kernel<true, true><<<N, 256, 0, stream>>>(bufH, row_ptr, csr_src, csr_norm,
                                                            dinv, b2, bufX, a_hi, a_lo);
        gemm_mfma_kernel<<<gemm_grid, 256, 0, stream>>>(a_hi, a_lo, wt_hi[2], wt_lo[2], bufH, N);
        aggregate_kernel<false, false><<<N, 256, 0, stream>>>(bufH, row_ptr, csr_src, csr_norm,
                                                              dinv, b3, bufX, a_hi, a_lo);
        pool_kernel<<<G, 256, 0, stream>>>(bufX, start, pool);
    };
    encode(x_a, ei_a, batch_a, pool_a);
    encode(x_b, ei_b, batch_b, pool_b);
    pdist_kernel<<<G, 64, 0, stream>>>(pool_a, pool_b, out);
}

// Round 7
// 1109.115 us; speedup vs baseline: 1.7198x; 1.7198x over previous
//
#include <hip/hip_runtime.h>
#include <hip/hip_fp16.h>

// SiameseBrainNet: 3-layer GCN encoder (shared weights) x2 + mean-pool + pairwise distance.
// D = H = 512 hard-coded. Encoders fused along M (concat A|B). GEMMs: split-bf16 (hi/lo)
// 3-MFMA fp32 emulation; GEMM output stored fp16 to halve the gather bytes in aggregation.
// Aggregate edge loop unrolled x4 (independent loads) to fix the MLP/latency bound seen in
// round-4 counters (3.77 TB/s @ 1 outstanding load/thread).

typedef short bf16x8 __attribute__((ext_vector_type(8)));
typedef float f32x4 __attribute__((ext_vector_type(4)));

__device__ __forceinline__ unsigned short f2bf(float f) {
    union { float f; unsigned u; } v; v.f = f;
    unsigned r = (v.u + 0x7fffu + ((v.u >> 16) & 1u)) >> 16;  // RNE
    return (unsigned short)r;
}
__device__ __forceinline__ float bf2f(unsigned short h) {
    union { unsigned u; float f; } v; v.u = ((unsigned)h) << 16;
    return v.f;
}

__device__ __forceinline__ void gload16(const unsigned short* g, unsigned short* lds) {
    __builtin_amdgcn_global_load_lds(
        (const __attribute__((address_space(1))) unsigned int*)g,
        (__attribute__((address_space(3))) unsigned int*)lds, 16, 0, 0);
}

// ---------------- CSR build ----------------

__global__ __launch_bounds__(256) void deg_kernel(const int* __restrict__ dst,
                                                  int* __restrict__ deg, int e) {
    int i = blockIdx.x * 256 + threadIdx.x;
    if (i < e) atomicAdd(&deg[dst[i]], 1);
}

// scan + dinv fused; grid = 2 (one block per encoder).
__global__ __launch_bounds__(1024) void scan2_kernel(const int* __restrict__ deg_all,
                                                     int* __restrict__ rp_all,
                                                     int* __restrict__ cur_all,
                                                     float* __restrict__ dinv_all, int n) {
    int enc = blockIdx.x;
    const int* deg = deg_all + (size_t)enc * n;
    int* row_ptr = rp_all + (size_t)enc * (n + 1);
    int* cursor = cur_all + (size_t)enc * n;
    float* dinv = dinv_all + (size_t)enc * n;

    __shared__ int sums[1024];
    int t = threadIdx.x;
    int chunk = (n + 1023) >> 10;
    int beg = t * chunk;
    int end = beg + chunk;
    if (beg > n) beg = n;
    if (end > n) end = n;
    int s = 0;
    for (int i = beg; i < end; ++i) s += deg[i];
    sums[t] = s;
    __syncthreads();
    for (int off = 1; off < 1024; off <<= 1) {
        int v = (t >= off) ? sums[t - off] : 0;
        __syncthreads();
        sums[t] += v;
        __syncthreads();
    }
    int run = sums[t] - s;
    for (int i = beg; i < end; ++i) {
        row_ptr[i] = run;
        cursor[i] = run;
        dinv[i] = rsqrtf((float)deg[i] + 1.0f);  // self-loop: deg+1
        run += deg[i];
    }
    if (t == 1023) row_ptr[n] = sums[1023];
}

// packed edge: {src, norm}
__global__ __launch_bounds__(256) void fill_kernel(const int* __restrict__ src,
                                                   const int* __restrict__ dst,
                                                   const float* __restrict__ dinv,
                                                   int* __restrict__ cursor,
                                                   int2* __restrict__ edges, int e) {
    int i = blockIdx.x * 256 + threadIdx.x;
    if (i >= e) return;
    int s = src[i], d = dst[i];
    int p = atomicAdd(&cursor[d], 1);
    int2 pr;
    pr.x = s;
    pr.y = __float_as_int(dinv[s] * dinv[d]);
    edges[p] = pr;
}

// ---------------- graph ranges from sorted batch ----------------

__global__ __launch_bounds__(256) void ranges_kernel(const int* __restrict__ batch,
                                                     int* __restrict__ start, int n, int g) {
    int i = blockIdx.x * 256 + threadIdx.x;
    if (i >= n) return;
    int b = batch[i];
    if (i == 0) {
        for (int k = 0; k <= b; ++k) start[k] = 0;
    } else {
        int pb = batch[i - 1];
        for (int k = pb + 1; k <= b; ++k) start[k] = i;
    }
    if (i == n - 1) {
        for (int k = b + 1; k <= g; ++k) start[k] = n;
    }
}

// ---------------- W pre-transpose + bf16 hi/lo split ----------------

__global__ __launch_bounds__(256) void wsplit_kernel(const float* __restrict__ W,
                                                     unsigned short* __restrict__ Wt_hi,
                                                     unsigned short* __restrict__ Wt_lo) {
    __shared__ float tile[32][33];
    int b = blockIdx.x;
    int k0 = (b & 15) * 32, n0 = (b >> 4) * 32;
    int t = threadIdx.x;
    int tc = t & 31, tr = t >> 5;
#pragma unroll
    for (int it = 0; it < 4; ++it)
        tile[tr + it * 8][tc] = W[(size_t)(k0 + tr + it * 8) * 512 + n0 + tc];
    __syncthreads();
#pragma unroll
    for (int it = 0; it < 4; ++it) {
        int n = tr + it * 8;
        float v = tile[tc][n];
        unsigned short hi = f2bf(v);
        unsigned short lo = f2bf(v - bf2f(hi));
        Wt_hi[(size_t)(n0 + n) * 512 + k0 + tc] = hi;
        Wt_lo[(size_t)(n0 + n) * 512 + k0 + tc] = lo;
    }
}

// ---------------- A bf16 hi/lo split (layer-1 input only) ----------------

__global__ __launch_bounds__(256) void asplit_kernel(const float* __restrict__ A,
                                                     unsigned short* __restrict__ A_hi,
                                                     unsigned short* __restrict__ A_lo,
                                                     int n4) {
    int i = blockIdx.x * 256 + threadIdx.x;
    if (i >= n4) return;
    float4 v = ((const float4*)A)[i];
    ushort4 h, l;
    h.x = f2bf(v.x); l.x = f2bf(v.x - bf2f(h.x));
    h.y = f2bf(v.y); l.y = f2bf(v.y - bf2f(h.y));
    h.z = f2bf(v.z); l.z = f2bf(v.z - bf2f(h.z));
    h.w = f2bf(v.w); l.w = f2bf(v.w - bf2f(h.w));
    ((ushort4*)A_hi)[i] = h;
    ((ushort4*)A_lo)[i] = l;
}

// ---------------- split-bf16 MFMA GEMM: C16[M x 512] = A[M x 512] @ W[512 x 512] ----------------
// BM=128 BN=128 BK=32, 256 threads (4 waves, 2x2), per-wave 64x64 via 4x4 frags of 16x16x32.
// A pre-split [m][k] bf16; B pre-transposed+split [n][k] bf16. Output fp16.
// Staging: global_load_lds dwordx4, linear LDS (wave-uniform dest + lane*16 rule).

__global__ __launch_bounds__(256) void gemm_mfma_kernel(const unsigned short* __restrict__ A_hi,
                                                        const unsigned short* __restrict__ A_lo,
                                                        const unsigned short* __restrict__ Bt_hi,
                                                        const unsigned short* __restrict__ Bt_lo,
                                                        __half* __restrict__ C, int M) {
    __shared__ unsigned short As_hi[128][32], As_lo[128][32];
    __shared__ unsigned short Bs_hi[128][32], Bs_lo[128][32];
    int nb = blockIdx.x & 3;
    int mb = blockIdx.x >> 2;
    int row0 = mb * 128, col0 = nb * 128;
    int t = threadIdx.x;
    int lane = t & 63, w = t >> 6;
    int wm = w >> 1, wn = w & 1;
    int r = lane & 15, g = lane >> 4;

    f32x4 acc[4][4] = {};

    int r4 = t >> 2;
    int kq = (t & 3) * 8;

    for (int k0 = 0; k0 < 512; k0 += 32) {
#pragma unroll
        for (int i = 0; i < 2; ++i) {
            int ldsrow = i * 64 + w * 16;
            gload16(A_hi + (size_t)(row0 + i * 64 + r4) * 512 + k0 + kq, &As_hi[ldsrow][0]);
            gload16(A_lo + (size_t)(row0 + i * 64 + r4) * 512 + k0 + kq, &As_lo[ldsrow][0]);
            gload16(Bt_hi + (size_t)(col0 + i * 64 + r4) * 512 + k0 + kq, &Bs_hi[ldsrow][0]);
            gload16(Bt_lo + (size_t)(col0 + i * 64 + r4) * 512 + k0 + kq, &Bs_lo[ldsrow][0]);
        }
        __syncthreads();

        bf16x8 ah[4], al[4], bh[4], bl[4];
#pragma unroll
        for (int m = 0; m < 4; ++m) {
            int rr = wm * 64 + m * 16 + r;
            ah[m] = *(const bf16x8*)&As_hi[rr][g * 8];
            al[m] = *(const bf16x8*)&As_lo[rr][g * 8];
        }
#pragma unroll
        for (int n = 0; n < 4; ++n) {
            int cc = wn * 64 + n * 16 + r;
            bh[n] = *(const bf16x8*)&Bs_hi[cc][g * 8];
            bl[n] = *(const bf16x8*)&Bs_lo[cc][g * 8];
        }
#pragma unroll
        for (int m = 0; m < 4; ++m)
#pragma unroll
            for (int n = 0; n < 4; ++n) {
                acc[m][n] = __builtin_amdgcn_mfma_f32_16x16x32_bf16(al[m], bh[n], acc[m][n], 0, 0, 0);
                acc[m][n] = __builtin_amdgcn_mfma_f32_16x16x32_bf16(ah[m], bl[n], acc[m][n], 0, 0, 0);
                acc[m][n] = __builtin_amdgcn_mfma_f32_16x16x32_bf16(ah[m], bh[n], acc[m][n], 0, 0, 0);
            }
        __syncthreads();
    }

#pragma unroll
    for (int m = 0; m < 4; ++m)
#pragma unroll
        for (int j = 0; j < 4; ++j) {
            int rr = row0 + wm * 64 + m * 16 + g * 4 + j;
            if (rr < M) {
#pragma unroll
                for (int n = 0; n < 4; ++n)
                    C[(size_t)rr * 512 + col0 + wn * 64 + n * 16 + r] =
                        __float2half(acc[m][n][j]);
            }
        }
}

// ---------------- fused aggregation (both encoders): one block per dst node ----------------
// agg[d] = sum_{e: dst=d} h16[src]*norm + h16[d]*dinv[d]^2 + b ; optional relu;
// output either bf16 hi/lo (next GEMM input) or fp32 (pool input).
// Edge loop unrolled x4 with independent loads -> 4 outstanding gathers per thread.

template <bool RELU, bool SPLIT>
__global__ __launch_bounds__(256) void aggregate_kernel(const __half* __restrict__ H,  // [2N][512]
                                                        const int* __restrict__ rp_all,
                                                        const int2* __restrict__ ed_all,
                                                        const float* __restrict__ dinv_all,
                                                        const float* __restrict__ bias,
                                                        float* __restrict__ X,
                                                        unsigned short* __restrict__ Xhi,
                                                        unsigned short* __restrict__ Xlo,
                                                        int n, int e) {
    int dg = blockIdx.x;           // global row (concat)
    bool isB = dg >= n;
    int d = isB ? dg - n : dg;     // local node id
    const int* rp = rp_all + (isB ? (size_t)(n + 1) : 0);
    const int2* ed = ed_all + (isB ? (size_t)e : 0);
    const float* dv = dinv_all + (isB ? (size_t)n : 0);
    const __half* Hb = H + (isB ? (size_t)n * 512 : 0);

    int t = threadIdx.x;
    int beg = rp[d], end = rp[d + 1];
    float ax = 0.f, ay = 0.f;
    int j = beg;
    for (; j + 4 <= end; j += 4) {
        int2 e0 = ed[j], e1 = ed[j + 1], e2 = ed[j + 2], e3 = ed[j + 3];
        // 4 independent gathers in flight
        __half2 h0 = *(const __half2*)(Hb + (size_t)e0.x * 512 + t * 2);
        __half2 h1 = *(const __half2*)(Hb + (size_t)e1.x * 512 + t * 2);
        __half2 h2 = *(const __half2*)(Hb + (size_t)e2.x * 512 + t * 2);
        __half2 h3 = *(const __half2*)(Hb + (size_t)e3.x * 512 + t * 2);
        float2 f0 = __half22float2(h0), f1 = __half22float2(h1);
        float2 f2 = __half22float2(h2), f3 = __half22float2(h3);
        float w0 = __int_as_float(e0.y), w1 = __int_as_float(e1.y);
        float w2 = __int_as_float(e2.y), w3 = __int_as_float(e3.y);
        ax += w0 * f0.x + w1 * f1.x + w2 * f2.x + w3 * f3.x;
        ay += w0 * f0.y + w1 * f1.y + w2 * f2.y + w3 * f3.y;
    }
    for (; j < end; ++j) {
        int2 ej = ed[j];
        float w = __int_as_float(ej.y);
        float2 f = __half22float2(*(const __half2*)(Hb + (size_t)ej.x * 512 + t * 2));
        ax += w * f.x;
        ay += w * f.y;
    }
    float di = dv[d];
    float self = di * di;
    float2 hd = __half22float2(*(const __half2*)(Hb + (size_t)d * 512 + t * 2));
    float2 bb = *(const float2*)(bias + t * 2);
    float ox = ax + self * hd.x + bb.x;
    float oy = ay + self * hd.y + bb.y;
    if (RELU) {
        ox = fmaxf(ox, 0.f);
        oy = fmaxf(oy, 0.f);
    }
    if (SPLIT) {
        unsigned short hx = f2bf(ox), hy = f2bf(oy);
        unsigned short lx = f2bf(ox - bf2f(hx)), ly = f2bf(oy - bf2f(hy));
        *(ushort2*)(Xhi + (size_t)dg * 512 + t * 2) = make_ushort2(hx, hy);
        *(ushort2*)(Xlo + (size_t)dg * 512 + t * 2) = make_ushort2(lx, ly);
    } else {
        *(float2*)(X + (size_t)dg * 512 + t * 2) = make_float2(ox, oy);
    }
}

// ---------------- mean pool over sorted-batch ranges (both encoders) ----------------

__global__ __launch_bounds__(256) void pool_kernel(const float* __restrict__ X,  // [2N][512]
                                                   const int* __restrict__ startA,
                                                   const int* __restrict__ startB,
                                                   float* __restrict__ pool,  // [2G][512]
                                                   int n, int gcount) {
    int g = blockIdx.x;
    bool isB = g >= gcount;
    const int* st = isB ? startB : startA;
    int gl = isB ? g - gcount : g;
    const float* Xb = X + (isB ? (size_t)n * 512 : 0);
    int t = threadIdx.x;
    int s = st[gl], e = st[gl + 1];
    float ax = 0.f, ay = 0.f;
    int i = s;
    for (; i + 2 <= e; i += 2) {
        float2 v0 = *(const float2*)(Xb + (size_t)i * 512 + t * 2);
        float2 v1 = *(const float2*)(Xb + (size_t)(i + 1) * 512 + t * 2);
        ax += v0.x + v1.x;
        ay += v0.y + v1.y;
    }
    for (; i < e; ++i) {
        float2 v = *(const float2*)(Xb + (size_t)i * 512 + t * 2);
        ax += v.x;
        ay += v.y;
    }
    float cnt = fmaxf((float)(e - s), 1.0f);
    *(float2*)(pool + (size_t)g * 512 + t * 2) = make_float2(ax / cnt, ay / cnt);
}

// ---------------- pairwise distance ----------------

__global__ __launch_bounds__(64) void pdist_kernel(const float* __restrict__ pool,
                                                   float* __restrict__ out, int gcount) {
    int g = blockIdx.x;
    int t = threadIdx.x;
    const float* pa = pool + (size_t)g * 512;
    const float* pb = pool + (size_t)(gcount + g) * 512;
    float s = 0.f;
    for (int i = t; i < 512; i += 64) {
        float d = pa[i] - pb[i] + 1e-6f;
        s += d * d;
    }
#pragma unroll
    for (int off = 32; off; off >>= 1) s += __shfl_down(s, off);
    if (t == 0) out[g] = sqrtf(s);
}

// ---------------- launch ----------------

extern "C" void kernel_launch(void* const* d_in, const int* in_sizes, int n_in,
                              void* d_out, int out_size, void* d_ws, size_t ws_size,
                              hipStream_t stream) {
    const float* x_a = (const float*)d_in[0];
    const int* ei_a = (const int*)d_in[1];
    const int* batch_a = (const int*)d_in[2];
    const float* x_b = (const float*)d_in[3];
    const int* ei_b = (const int*)d_in[4];
    const int* batch_b = (const int*)d_in[5];
    const float* W1 = (const float*)d_in[6];
    const float* b1 = (const float*)d_in[7];
    const float* W2 = (const float*)d_in[8];
    const float* b2 = (const float*)d_in[9];
    const float* W3 = (const float*)d_in[10];
    const float* b3 = (const float*)d_in[11];
    float* out = (float*)d_out;

    const int N = in_sizes[0] / 512;
    const int E = in_sizes[1] / 2;
    const int G = out_size;
    const int M = 2 * N;                      // concat A|B
    const int Mpad = ((M + 127) / 128) * 128; // GEMM tail rows read junk, never stored

    char* ws = (char*)d_ws;
    size_t off = 0;
    auto alloc = [&](size_t bytes) -> void* {
        void* p = ws + off;
        off = (off + bytes + 255) & ~(size_t)255;
        return p;
    };
    __half* bufH16 = (__half*)alloc((size_t)Mpad * 512 * 2);
    // a_hi | a_lo block; also aliased as fp32 X for layer-3 output (a_hi/a_lo dead by then)
    char* abblock = (char*)alloc((size_t)Mpad * 512 * 4);
    unsigned short* a_hi = (unsigned short*)abblock;
    unsigned short* a_lo = a_hi + (size_t)Mpad * 512;
    float* bufX = (float*)abblock;
    int* deg = (int*)alloc((size_t)2 * N * 4);        // [A | B]
    float* dinv = (float*)alloc((size_t)2 * N * 4);   // [A | B]
    int* rp = (int*)alloc((size_t)2 * (N + 1) * 4);   // [A | B]
    int* cur = (int*)alloc((size_t)2 * N * 4);        // [A | B]
    int2* ed = (int2*)alloc((size_t)2 * E * 8);       // [A | B]
    int* startA = (int*)alloc((size_t)(G + 1) * 4);
    int* startB = (int*)alloc((size_t)(G + 1) * 4);
    float* pool = (float*)alloc((size_t)2 * G * 512 * 4);
    unsigned short* wt_hi[3];
    unsigned short* wt_lo[3];
    for (int i = 0; i < 3; ++i) {
        wt_hi[i] = (unsigned short*)alloc((size_t)512 * 512 * 2);
        wt_lo[i] = (unsigned short*)alloc((size_t)512 * 512 * 2);
    }

    const int ebl = (E + 255) / 256;
    const int nbl = (N + 255) / 256;
    const int gemm_grid = 4 * (Mpad / 128);
    const int n4 = N * 512 / 4;
    const int abl = (n4 + 255) / 256;

    // weights: pre-transpose + split (same every call; graph-capture safe)
    wsplit_kernel<<<256, 256, 0, stream>>>(W1, wt_hi[0], wt_lo[0]);
    wsplit_kernel<<<256, 256, 0, stream>>>(W2, wt_hi[1], wt_lo[1]);
    wsplit_kernel<<<256, 256, 0, stream>>>(W3, wt_hi[2], wt_lo[2]);

    // CSR build (A and B), batch ranges
    hipMemsetAsync(deg, 0, (size_t)2 * N * 4, stream);  // deg is one contiguous 2N block
    deg_kernel<<<ebl, 256, 0, stream>>>(ei_a + E, deg, E);
    deg_kernel<<<ebl, 256, 0, stream>>>(ei_b + E, deg + N, E);
    scan2_kernel<<<2, 1024, 0, stream>>>(deg, rp, cur, dinv, N);
    fill_kernel<<<ebl, 256, 0, stream>>>(ei_a, ei_a + E, dinv, cur, ed, E);
    fill_kernel<<<ebl, 256, 0, stream>>>(ei_b, ei_b + E, dinv + N, cur + N, ed + E, E);
    ranges_kernel<<<nbl, 256, 0, stream>>>(batch_a, startA, N, G);
    ranges_kernel<<<nbl, 256, 0, stream>>>(batch_b, startB, N, G);

    // layer-1 input: split x_a|x_b into concat bf16 hi/lo
    asplit_kernel<<<abl, 256, 0, stream>>>(x_a, a_hi, a_lo, n4);
    asplit_kernel<<<abl, 256, 0, stream>>>(x_b, a_hi + (size_t)N * 512, a_lo + (size_t)N * 512, n4);

    // layer 1
    gemm_mfma_kernel<<<gemm_grid, 256, 0, stream>>>(a_hi, a_lo, wt_hi[0], wt_lo[0], bufH16, M);
    aggregate_kernel<true, true><<<M, 256, 0, stream>>>(bufH16, rp, ed, dinv, b1,
                                                        bufX, a_hi, a_lo, N, E);
    // layer 2
    gemm_mfma_kernel<<<gemm_grid, 256, 0, stream>>>(a_hi, a_lo, wt_hi[1], wt_lo[1], bufH16, M);
    aggregate_kernel<true, true><<<M, 256, 0, stream>>>(bufH16, rp, ed, dinv, b2,
                                                        bufX, a_hi, a_lo, N, E);
    // layer 3 (fp32 out into the dead a_hi/a_lo block)
    gemm_mfma_kernel<<<gemm_grid, 256, 0, stream>>>(a_hi, a_lo, wt_hi[2], wt_lo[2], bufH16, M);
    aggregate_kernel<false, false><<<M, 256, 0, stream>>>(bufH16, rp, ed, dinv, b3,
                                                          bufX, a_hi, a_lo, N, E);

    // pool + distance
    pool_kernel<<<2 * G, 256, 0, stream>>>(bufX, startA, startB, pool, N, G);
    pdist_kernel<<<G, 64, 0, stream>>>(pool, out, G);
}